// Round 2
// baseline (312.088 us; speedup 1.0000x reference)
//
#include <hip/hip_runtime.h>
#include <hip/hip_bf16.h>

#define B_    8
#define L_    1024
#define DM_   768
#define H_    12
#define DH_   64
#define NQKV_ 2304
#define MTOK_ 8192
#define SCALE 0.125f
#define LDT_  72   // padded LDS stride (bf16 elems): 144 B -> only 2-way bank aliasing (free, m136)

typedef short bf16x8 __attribute__((ext_vector_type(8)));
typedef float f32x4 __attribute__((ext_vector_type(4)));

#define N_X   (MTOK_*DM_)           // 6291456
#define N_WQ  (NQKV_*DM_)           // 1769472
#define N_WO  (DM_*DM_)             // 589824
#define N_CVT (N_X + N_WQ + N_WO)   // 8650752 (all divisible by 4)

// f32 -> bf16 round-to-nearest-even, as raw ushort
static __device__ __forceinline__ unsigned short f2bu(float f) {
    unsigned int x = __float_as_uint(f);
    x = (x + 0x7fffu + ((x >> 16) & 1u)) >> 16;
    return (unsigned short)x;
}

// One kernel converts all three f32 tensors to bf16 (segment dispatch on flat index).
__global__ void cvt_all_k(const float* __restrict__ x, const float* __restrict__ wq,
                          const float* __restrict__ wo,
                          unsigned short* __restrict__ xb, unsigned short* __restrict__ wqb,
                          unsigned short* __restrict__ wob) {
    int i = (blockIdx.x * blockDim.x + threadIdx.x) * 4;
    if (i >= N_CVT) return;
    const float* src; unsigned short* dst; int j = i;
    if (j < N_X)              { src = x;  dst = xb;  }
    else if ((j -= N_X) < N_WQ) { src = wq; dst = wqb; }
    else                      { j -= N_WQ; src = wo; dst = wob; }
    float4 v = *reinterpret_cast<const float4*>(src + j);
    ushort4 o;
    o.x = f2bu(v.x); o.y = f2bu(v.y); o.z = f2bu(v.z); o.w = f2bu(v.w);
    *reinterpret_cast<ushort4*>(dst + j) = o;
}

// SQ[b,h,i] = Q[b,h,perm[h,i]] over flattened (n*dh)
__global__ void shuffle_q_k(const unsigned short* __restrict__ Qb, const int* __restrict__ perms,
                            unsigned short* __restrict__ SQb) {
    int idx = blockIdx.x * blockDim.x + threadIdx.x;   // [0, 8*12*65536)
    int i  = idx & 65535;
    int bh = idx >> 16;
    int h  = bh % H_;
    int p  = perms[h * (L_ * DH_) + i];
    SQb[(bh << 16) + i] = Qb[(bh << 16) + p];
}

// Bijective XCD swizzle (grid size must be divisible by 8 — all our grids are).
static __device__ __forceinline__ int xcd_swz(int bid, int nwg) {
    int cpx = nwg >> 3;
    return (bid & 7) * cpx + (bid >> 3);
}

// C = A[M,K] * Bw[N,K]^T  (both bf16 in ws), 128x128 tile, 4 waves, 4x4 16x16x32 frags/wave.
// mode 0: scatter into head-major Q/K/V bf16 buffers (fuses to_heads)
// mode 1: f32 output + bias
__global__ __launch_bounds__(256) void gemm_bt_k(
    const unsigned short* __restrict__ A,
    const unsigned short* __restrict__ Bw,
    int M, int N, int K, int mode,
    unsigned short* __restrict__ Qb, unsigned short* __restrict__ Kb, unsigned short* __restrict__ Vb,
    float* __restrict__ Cout, const float* __restrict__ bias)
{
    __shared__ __align__(16) unsigned short sA[128 * LDT_];
    __shared__ __align__(16) unsigned short sB[128 * LDT_];

    int t = threadIdx.x;
    int lane = t & 63, w = t >> 6;
    int wr = w >> 1, wc = w & 1;
    int lr = lane & 15, lg = lane >> 4;

    int nbx = N >> 7;
    int bid = xcd_swz(blockIdx.y * nbx + blockIdx.x, (M >> 7) * nbx);
    int m0 = (bid / nbx) * 128, n0 = (bid % nbx) * 128;

    f32x4 acc[4][4];
    #pragma unroll
    for (int i = 0; i < 4; ++i)
        #pragma unroll
        for (int j = 0; j < 4; ++j) acc[i][j] = (f32x4){0.f, 0.f, 0.f, 0.f};

    int r0 = t >> 3, c0 = (t & 7) * 8;

    for (int kt = 0; kt < K; kt += 64) {
        __syncthreads();   // previous iteration's reads done before overwrite
        #pragma unroll
        for (int c = 0; c < 4; ++c) {
            int row = r0 + c * 32;
            uint4 va = *reinterpret_cast<const uint4*>(A + (size_t)(m0 + row) * K + kt + c0);
            *reinterpret_cast<uint4*>(&sA[row * LDT_ + c0]) = va;
            uint4 vb = *reinterpret_cast<const uint4*>(Bw + (size_t)(n0 + row) * K + kt + c0);
            *reinterpret_cast<uint4*>(&sB[row * LDT_ + c0]) = vb;
        }
        __syncthreads();
        #pragma unroll
        for (int kk = 0; kk < 2; ++kk) {
            bf16x8 af[4], bfr[4];
            #pragma unroll
            for (int mi = 0; mi < 4; ++mi)
                af[mi] = *reinterpret_cast<const bf16x8*>(&sA[(wr*64 + mi*16 + lr) * LDT_ + kk*32 + lg*8]);
            #pragma unroll
            for (int ni = 0; ni < 4; ++ni)
                bfr[ni] = *reinterpret_cast<const bf16x8*>(&sB[(wc*64 + ni*16 + lr) * LDT_ + kk*32 + lg*8]);
            #pragma unroll
            for (int mi = 0; mi < 4; ++mi)
                #pragma unroll
                for (int ni = 0; ni < 4; ++ni)
                    acc[mi][ni] = __builtin_amdgcn_mfma_f32_16x16x32_bf16(af[mi], bfr[ni], acc[mi][ni], 0, 0, 0);
        }
    }

    // C/D layout (verified m89/m91): col = lane&15, row = (lane>>4)*4 + reg
    if (mode == 0) {
        #pragma unroll
        for (int mi = 0; mi < 4; ++mi)
            #pragma unroll
            for (int ni = 0; ni < 4; ++ni)
                #pragma unroll
                for (int r = 0; r < 4; ++r) {
                    int gm = m0 + wr*64 + mi*16 + lg*4 + r;   // token index
                    int gc = n0 + wc*64 + ni*16 + lr;         // qkv column
                    int bidx = gm >> 10, tok = gm & 1023;
                    int which = gc / DM_;
                    int rem = gc - which * DM_;
                    int hh = rem >> 6, d = rem & 63;
                    unsigned short* dst = (which == 0) ? Qb : ((which == 1) ? Kb : Vb);
                    dst[(((bidx * H_ + hh) * L_) + tok) * DH_ + d] = f2bu(acc[mi][ni][r]);
                }
    } else {
        #pragma unroll
        for (int mi = 0; mi < 4; ++mi)
            #pragma unroll
            for (int ni = 0; ni < 4; ++ni)
                #pragma unroll
                for (int r = 0; r < 4; ++r) {
                    int gm = m0 + wr*64 + mi*16 + lg*4 + r;
                    int gc = n0 + wc*64 + ni*16 + lr;
                    Cout[(size_t)gm * N + gc] = acc[mi][ni][r] + bias[gc];
                }
    }
}

// Flash attention: block = (b,h, 64 q rows); 4 waves x 16 rows; KV tiles of 64.
__global__ __launch_bounds__(256) void attn_k(
    const unsigned short* __restrict__ SQb, const unsigned short* __restrict__ Kb,
    const unsigned short* __restrict__ Vb, unsigned short* __restrict__ Ob)
{
    __shared__ __align__(16) unsigned short sQ[64 * LDT_];
    __shared__ __align__(16) unsigned short sK[64 * LDT_];
    __shared__ __align__(16) unsigned short sVT[64 * LDT_];   // V transposed: [d][key]
    __shared__ __align__(16) unsigned short sP[4][16 * LDT_];

    int t = threadIdx.x;
    int lane = t & 63, w = t >> 6;
    int lr = lane & 15, lg = lane >> 4;

    // swizzle so all 16 q-tiles of one (b,h) stay on one XCD (K/V L2 locality)
    int bid = xcd_swz(blockIdx.y * gridDim.x + blockIdx.x, gridDim.x * gridDim.y);
    int bh = bid >> 4;                 // gridDim.x == 16
    int q0 = (bid & 15) * 64;
    int b = bh / H_, h = bh - b * H_;

    const unsigned short* Qp = SQb + (bh << 16);
    const unsigned short* Kp = Kb + (bh << 16);
    const unsigned short* Vp = Vb + (bh << 16);

    int r0 = t >> 3, c0 = (t & 7) * 8;
    #pragma unroll
    for (int c = 0; c < 2; ++c) {
        int row = r0 + c * 32;
        *reinterpret_cast<uint4*>(&sQ[row * LDT_ + c0]) =
            *reinterpret_cast<const uint4*>(Qp + (q0 + row) * 64 + c0);
    }

    f32x4 accO[4];
    float m_row[4], l_row[4];
    #pragma unroll
    for (int i = 0; i < 4; ++i) { accO[i] = (f32x4){0.f,0.f,0.f,0.f}; m_row[i] = -1e30f; l_row[i] = 0.f; }

    for (int kv0 = 0; kv0 < L_; kv0 += 64) {
        __syncthreads();   // prior reads of sK/sVT/sP done
        #pragma unroll
        for (int c = 0; c < 2; ++c) {
            int row = r0 + c * 32;
            *reinterpret_cast<uint4*>(&sK[row * LDT_ + c0]) =
                *reinterpret_cast<const uint4*>(Kp + (kv0 + row) * 64 + c0);
            uint4 vv = *reinterpret_cast<const uint4*>(Vp + (kv0 + row) * 64 + c0);
            unsigned short tmp[8];
            *reinterpret_cast<uint4*>(tmp) = vv;
            #pragma unroll
            for (int j = 0; j < 8; ++j) sVT[(c0 + j) * LDT_ + row] = tmp[j];
        }
        __syncthreads();

        // S = (SQ tile) x K^T
        f32x4 accS[4];
        #pragma unroll
        for (int i = 0; i < 4; ++i) accS[i] = (f32x4){0.f,0.f,0.f,0.f};
        #pragma unroll
        for (int kk = 0; kk < 2; ++kk) {
            bf16x8 aq = *reinterpret_cast<const bf16x8*>(&sQ[(w*16 + lr) * LDT_ + kk*32 + lg*8]);
            #pragma unroll
            for (int nb = 0; nb < 4; ++nb) {
                bf16x8 bk = *reinterpret_cast<const bf16x8*>(&sK[(nb*16 + lr) * LDT_ + kk*32 + lg*8]);
                accS[nb] = __builtin_amdgcn_mfma_f32_16x16x32_bf16(aq, bk, accS[nb], 0, 0, 0);
            }
        }
        #pragma unroll
        for (int nb = 0; nb < 4; ++nb) accS[nb] *= SCALE;

        // online softmax; acc row = lg*4 + r, col = lr (keys) -> row-reduce over 16 lanes
        float mnew[4], alpha[4], rowsum[4];
        #pragma unroll
        for (int r = 0; r < 4; ++r) {
            float tm = fmaxf(fmaxf(accS[0][r], accS[1][r]), fmaxf(accS[2][r], accS[3][r]));
            #pragma unroll
            for (int off = 1; off < 16; off <<= 1) tm = fmaxf(tm, __shfl_xor(tm, off, 16));
            mnew[r]  = fmaxf(m_row[r], tm);
            alpha[r] = __expf(m_row[r] - mnew[r]);
            rowsum[r] = 0.f;
        }
        #pragma unroll
        for (int nb = 0; nb < 4; ++nb)
            #pragma unroll
            for (int r = 0; r < 4; ++r) {
                float p = __expf(accS[nb][r] - mnew[r]);
                rowsum[r] += p;
                sP[w][(lg*4 + r) * LDT_ + nb*16 + lr] = f2bu(p);
            }
        #pragma unroll
        for (int r = 0; r < 4; ++r) {
            float rs = rowsum[r];
            #pragma unroll
            for (int off = 1; off < 16; off <<= 1) rs += __shfl_xor(rs, off, 16);
            l_row[r] = l_row[r] * alpha[r] + rs;
            m_row[r] = mnew[r];
        }
        #pragma unroll
        for (int nb = 0; nb < 4; ++nb)
            #pragma unroll
            for (int r = 0; r < 4; ++r) accO[nb][r] *= alpha[r];

        __syncthreads();   // sP visible

        // O += P x V
        #pragma unroll
        for (int kk = 0; kk < 2; ++kk) {
            bf16x8 ap = *reinterpret_cast<const bf16x8*>(&sP[w][lr * LDT_ + kk*32 + lg*8]);
            #pragma unroll
            for (int nb = 0; nb < 4; ++nb) {
                bf16x8 bv = *reinterpret_cast<const bf16x8*>(&sVT[(nb*16 + lr) * LDT_ + kk*32 + lg*8]);
                accO[nb] = __builtin_amdgcn_mfma_f32_16x16x32_bf16(ap, bv, accO[nb], 0, 0, 0);
            }
        }
    }

    // write O in [b, n, h*dh] layout (bf16) for the output GEMM
    #pragma unroll
    for (int nb = 0; nb < 4; ++nb)
        #pragma unroll
        for (int r = 0; r < 4; ++r) {
            int q = q0 + w*16 + lg*4 + r;
            int d = nb*16 + lr;
            float o = accO[nb][r] / l_row[r];
            Ob[(b * L_ + q) * DM_ + h * DH_ + d] = f2bu(o);
        }
}

extern "C" void kernel_launch(void* const* d_in, const int* in_sizes, int n_in,
                              void* d_out, int out_size, void* d_ws, size_t ws_size,
                              hipStream_t stream)
{
    const float* x     = (const float*)d_in[0];
    const float* w_qkv = (const float*)d_in[1];
    const float* w_out = (const float*)d_in[2];
    const float* b_out = (const float*)d_in[3];
    const int*   perms = (const int*)d_in[4];
    float* out = (float*)d_out;

    char* ws = (char*)d_ws;
    size_t off = 0;
    auto alloc_us = [&](size_t elems) -> unsigned short* {
        unsigned short* p = (unsigned short*)(ws + off);
        off += (elems * 2 + 255) & ~(size_t)255;
        return p;
    };
    unsigned short* xb    = alloc_us((size_t)MTOK_ * DM_);
    unsigned short* wqkvb = alloc_us((size_t)NQKV_ * DM_);
    unsigned short* woutb = alloc_us((size_t)DM_ * DM_);
    unsigned short* Qb    = alloc_us((size_t)B_ * H_ * L_ * DH_);
    unsigned short* Kb2   = alloc_us((size_t)B_ * H_ * L_ * DH_);
    unsigned short* Vb2   = alloc_us((size_t)B_ * H_ * L_ * DH_);
    unsigned short* SQb   = alloc_us((size_t)B_ * H_ * L_ * DH_);
    unsigned short* Ob    = xb;   // reuse: xb dead after the QKV GEMM
    // total ws: ~67.6 MB

    cvt_all_k<<<(N_CVT/4 + 255)/256, 256, 0, stream>>>(x, w_qkv, w_out, xb, wqkvb, woutb);

    gemm_bt_k<<<dim3(NQKV_/128, MTOK_/128), 256, 0, stream>>>(
        xb, wqkvb, MTOK_, NQKV_, DM_, 0, Qb, Kb2, Vb2, nullptr, nullptr);

    shuffle_q_k<<<(B_*H_*L_*DH_)/256, 256, 0, stream>>>(Qb, perms, SQb);

    attn_k<<<dim3(L_/64, B_*H_), 256, 0, stream>>>(SQb, Kb2, Vb2, Ob);

    gemm_bt_k<<<dim3(DM_/128, MTOK_/128), 256, 0, stream>>>(
        Ob, woutb, MTOK_, DM_, DM_, 1, nullptr, nullptr, nullptr, out, b_out);
}

// Round 8
// 293.266 us; speedup vs baseline: 1.0642x; 1.0642x over previous
//
#include <hip/hip_runtime.h>
#include <hip/hip_bf16.h>

#define B_    8
#define L_    1024
#define DM_   768
#define H_    12
#define DH_   64
#define NQKV_ 2304
#define MTOK_ 8192
#define SCALE2 0.1803368801f   // (1/8) * log2(e): softmax computed in exp2 domain

typedef short bf16x8 __attribute__((ext_vector_type(8)));
typedef float f32x4 __attribute__((ext_vector_type(4)));

#define N_X   (MTOK_*DM_)
#define N_WQ  (NQKV_*DM_)
#define N_WO  (DM_*DM_)
#define N_CVT (N_X + N_WQ + N_WO)

// async global->LDS, 16B per lane; LDS dest = uniform base + lane*16 (linear),
// swizzling is done by permuting the per-lane GLOBAL source column (m173 pattern).
#define GLDS16(gp, sp) __builtin_amdgcn_global_load_lds( \
    (const __attribute__((address_space(1))) void*)(gp), \
    (__attribute__((address_space(3))) void*)(sp), 16, 0, 0)

// f32 -> bf16 RNE as raw ushort
static __device__ __forceinline__ unsigned short f2bu(float f) {
    unsigned int x = __float_as_uint(f);
    x = (x + 0x7fffu + ((x >> 16) & 1u)) >> 16;
    return (unsigned short)x;
}

__global__ void cvt_all_k(const float* __restrict__ x, const float* __restrict__ wq,
                          const float* __restrict__ wo,
                          unsigned short* __restrict__ xb, unsigned short* __restrict__ wqb,
                          unsigned short* __restrict__ wob) {
    int i = (blockIdx.x * blockDim.x + threadIdx.x) * 4;
    if (i >= N_CVT) return;
    const float* src; unsigned short* dst; int j = i;
    if (j < N_X)                { src = x;  dst = xb;  }
    else if ((j -= N_X) < N_WQ) { src = wq; dst = wqb; }
    else                        { j -= N_WQ; src = wo; dst = wob; }
    float4 v = *reinterpret_cast<const float4*>(src + j);
    ushort4 o;
    o.x = f2bu(v.x); o.y = f2bu(v.y); o.z = f2bu(v.z); o.w = f2bu(v.w);
    *reinterpret_cast<ushort4*>(dst + j) = o;
}

__global__ void shuffle_q_k(const unsigned short* __restrict__ Qb, const int* __restrict__ perms,
                            unsigned short* __restrict__ SQb) {
    int idx = blockIdx.x * blockDim.x + threadIdx.x;
    int i  = idx & 65535;
    int bh = idx >> 16;
    int h  = bh % H_;
    int p  = perms[h * (L_ * DH_) + i];
    SQb[(bh << 16) + i] = Qb[(bh << 16) + p];
}

static __device__ __forceinline__ int xcd_swz(int bid, int nwg) {
    int cpx = nwg >> 3;
    return (bid & 7) * cpx + (bid >> 3);
}

// C = A[M,K] * Bw[N,K]^T, 128x128 tile, BK=64, global_load_lds staging (m97 structure)
// LDS [128][64] linear; logical col-chunk cc stored at slot cc ^ (row&7)  (conflict-free reads)
// mode 0: scatter Q/K head-major + V TRANSPOSED [b,h][d][key]; mode 1: f32 + bias
__global__ __launch_bounds__(256) void gemm_bt_k(
    const unsigned short* __restrict__ A,
    const unsigned short* __restrict__ Bw,
    int M, int N, int K, int mode,
    unsigned short* __restrict__ Qb, unsigned short* __restrict__ Kb, unsigned short* __restrict__ VTb,
    float* __restrict__ Cout, const float* __restrict__ bias)
{
    __shared__ __align__(16) unsigned short sA[128 * 64];
    __shared__ __align__(16) unsigned short sB[128 * 64];

    int t = threadIdx.x;
    int lane = t & 63, w = t >> 6;
    int wr = w >> 1, wc = w & 1;
    int lr = lane & 15, lg = lane >> 4;

    int nbx = N >> 7;
    int bid = xcd_swz(blockIdx.y * nbx + blockIdx.x, (M >> 7) * nbx);
    int m0 = (bid / nbx) * 128, n0 = (bid % nbx) * 128;

    // staging geometry: chunk = 8 rows x 64 cols = 1KB; lane covers (row = ch*8 + lane>>3,
    // global col = ((lane&7) ^ (lane>>3))*8) -> LDS slot holds swizzled layout, still coalesced.
    int srow  = lane >> 3;
    int scol8 = ((lane & 7) ^ srow) * 8;

    f32x4 acc[4][4];
    #pragma unroll
    for (int i = 0; i < 4; ++i)
        #pragma unroll
        for (int j = 0; j < 4; ++j) acc[i][j] = (f32x4){0.f, 0.f, 0.f, 0.f};

    for (int kt = 0; kt < K; kt += 64) {
        __syncthreads();   // prev tile's fragment reads done
        #pragma unroll
        for (int i = 0; i < 4; ++i) {
            int ch = w * 4 + i;
            int row = ch * 8 + srow;
            GLDS16(A  + (size_t)(m0 + row) * K + kt + scol8, sA + ch * 512);
            GLDS16(Bw + (size_t)(n0 + row) * K + kt + scol8, sB + ch * 512);
        }
        __syncthreads();   // drains vmcnt -> LDS ready
        #pragma unroll
        for (int kk = 0; kk < 2; ++kk) {
            int cs = ((kk * 4 + lg) ^ (lr & 7)) << 3;   // swizzled col offset (elems)
            bf16x8 af[4], bfr[4];
            #pragma unroll
            for (int mi = 0; mi < 4; ++mi)
                af[mi] = *reinterpret_cast<const bf16x8*>(&sA[(wr*64 + mi*16 + lr) * 64 + cs]);
            #pragma unroll
            for (int ni = 0; ni < 4; ++ni)
                bfr[ni] = *reinterpret_cast<const bf16x8*>(&sB[(wc*64 + ni*16 + lr) * 64 + cs]);
            #pragma unroll
            for (int mi = 0; mi < 4; ++mi)
                #pragma unroll
                for (int ni = 0; ni < 4; ++ni)
                    acc[mi][ni] = __builtin_amdgcn_mfma_f32_16x16x32_bf16(af[mi], bfr[ni], acc[mi][ni], 0, 0, 0);
        }
    }

    // C/D layout: col = lane&15, row = (lane>>4)*4 + reg (m89/m91)
    if (mode == 0) {
        #pragma unroll
        for (int mi = 0; mi < 4; ++mi)
            #pragma unroll
            for (int ni = 0; ni < 4; ++ni)
                #pragma unroll
                for (int r = 0; r < 4; ++r) {
                    int gm = m0 + wr*64 + mi*16 + lg*4 + r;   // token
                    int gc = n0 + wc*64 + ni*16 + lr;         // qkv column
                    int bidx = gm >> 10, tok = gm & 1023;
                    int which = gc / DM_;
                    int rem = gc - which * DM_;
                    int hh = rem >> 6, d = rem & 63;
                    unsigned short v = f2bu(acc[mi][ni][r]);
                    if (which == 0)      Qb [(((bidx * H_ + hh) * L_) + tok) * DH_ + d] = v;
                    else if (which == 1) Kb [(((bidx * H_ + hh) * L_) + tok) * DH_ + d] = v;
                    else                 VTb[(((bidx * H_ + hh) * DH_) + d) * L_ + tok] = v;  // V^T
                }
    } else {
        #pragma unroll
        for (int mi = 0; mi < 4; ++mi)
            #pragma unroll
            for (int ni = 0; ni < 4; ++ni)
                #pragma unroll
                for (int r = 0; r < 4; ++r) {
                    int gm = m0 + wr*64 + mi*16 + lg*4 + r;
                    int gc = n0 + wc*64 + ni*16 + lr;
                    Cout[(size_t)gm * N + gc] = acc[mi][ni][r] + bias[gc];
                }
    }
}

// Flash attention. All LDS tiles [64][64] bf16, XOR-swizzled (slot cc = logical cc ^ (row&7)).
// K and V^T staged per tile via global_load_lds with pre-swizzled global column.
__global__ __launch_bounds__(256) void attn_k(
    const unsigned short* __restrict__ SQb, const unsigned short* __restrict__ Kb,
    const unsigned short* __restrict__ VTb, unsigned short* __restrict__ Ob)
{
    __shared__ __align__(16) unsigned short sQ [64 * 64];
    __shared__ __align__(16) unsigned short sK [64 * 64];
    __shared__ __align__(16) unsigned short sVT[64 * 64];   // [d][key], swizzled
    __shared__ __align__(16) unsigned short sP [4 * 16 * 64];

    int t = threadIdx.x;
    int lane = t & 63, w = t >> 6;
    int lr = lane & 15, lg = lane >> 4;

    int bid = xcd_swz(blockIdx.y * gridDim.x + blockIdx.x, gridDim.x * gridDim.y);
    int bh = bid >> 4;                  // gridDim.x == 16
    int q0 = (bid & 15) * 64;
    int b = bh / H_, h = bh - b * H_;

    const unsigned short* Qp  = SQb + (bh << 16);
    const unsigned short* Kp  = Kb  + (bh << 16);
    const unsigned short* VTp = VTb + (bh << 16);

    int srow  = lane >> 3;
    int scol8 = ((lane & 7) ^ srow) * 8;

    // stage Q once (8 chunks, 2 per wave)
    #pragma unroll
    for (int i = 0; i < 2; ++i) {
        int ch = w * 2 + i;
        int row = ch * 8 + srow;
        GLDS16(Qp + (size_t)(q0 + row) * 64 + scol8, sQ + ch * 512);
    }

    f32x4 accO[4];
    float m_row[4], l_row[4];
    #pragma unroll
    for (int i = 0; i < 4; ++i) { accO[i] = (f32x4){0.f,0.f,0.f,0.f}; m_row[i] = -1e30f; l_row[i] = 0.f; }

    for (int kv0 = 0; kv0 < L_; kv0 += 64) {
        __syncthreads();   // prev tile's sK/sVT reads done
        #pragma unroll
        for (int i = 0; i < 2; ++i) {
            int ch = w * 2 + i;
            int row = ch * 8 + srow;                       // key-row for K, d-row for V^T
            GLDS16(Kp  + (size_t)(kv0 + row) * 64 + scol8, sK  + ch * 512);
            GLDS16(VTp + (size_t)row * L_ + kv0 + scol8,   sVT + ch * 512);
        }
        __syncthreads();   // drain: tiles ready

        // S = Q x K^T  (contraction over d)
        f32x4 accS[4];
        #pragma unroll
        for (int i = 0; i < 4; ++i) accS[i] = (f32x4){0.f,0.f,0.f,0.f};
        #pragma unroll
        for (int kk = 0; kk < 2; ++kk) {
            int cs = ((kk * 4 + lg) ^ (lr & 7)) << 3;
            bf16x8 aq = *reinterpret_cast<const bf16x8*>(&sQ[(w*16 + lr) * 64 + cs]);
            #pragma unroll
            for (int nb = 0; nb < 4; ++nb) {
                bf16x8 bk = *reinterpret_cast<const bf16x8*>(&sK[(nb*16 + lr) * 64 + cs]);
                accS[nb] = __builtin_amdgcn_mfma_f32_16x16x32_bf16(aq, bk, accS[nb], 0, 0, 0);
            }
        }
        #pragma unroll
        for (int nb = 0; nb < 4; ++nb) accS[nb] *= SCALE2;   // into log2 domain

        // online softmax (exp2 domain); acc row = lg*4+r, col(key) = lr
        float mnew[4], alpha[4], rowsum[4];
        #pragma unroll
        for (int r = 0; r < 4; ++r) {
            float tm = fmaxf(fmaxf(accS[0][r], accS[1][r]), fmaxf(accS[2][r], accS[3][r]));
            #pragma unroll
            for (int off = 1; off < 16; off <<= 1) tm = fmaxf(tm, __shfl_xor(tm, off, 16));
            mnew[r]  = fmaxf(m_row[r], tm);
            alpha[r] = exp2f(m_row[r] - mnew[r]);
            rowsum[r] = 0.f;
        }
        #pragma unroll
        for (int nb = 0; nb < 4; ++nb)
            #pragma unroll
            for (int r = 0; r < 4; ++r) {
                float p = exp2f(accS[nb][r] - mnew[r]);
                rowsum[r] += p;
                int prow = lg * 4 + r;
                sP[w*1024 + prow*64 + ((((nb*2) + (lr >> 3)) ^ (prow & 7)) << 3) + (lr & 7)] = f2bu(p);
            }
        #pragma unroll
        for (int r = 0; r < 4; ++r) {
            float rs = rowsum[r];
            #pragma unroll
            for (int off = 1; off < 16; off <<= 1) rs += __shfl_xor(rs, off, 16);
            l_row[r] = l_row[r] * alpha[r] + rs;
            m_row[r] = mnew[r];
        }
        #pragma unroll
        for (int nb = 0; nb < 4; ++nb)
            #pragma unroll
            for (int r = 0; r < 4; ++r) accO[nb][r] *= alpha[r];

        // O += P x V  (sP is wave-private: no barrier needed; lgkmcnt orders same-wave LDS)
        #pragma unroll
        for (int kk = 0; kk < 2; ++kk) {
            int cs = ((kk * 4 + lg) ^ (lr & 7)) << 3;
            bf16x8 ap = *reinterpret_cast<const bf16x8*>(&sP[w*1024 + lr*64 + cs]);
            #pragma unroll
            for (int nb = 0; nb < 4; ++nb) {
                bf16x8 bv = *reinterpret_cast<const bf16x8*>(&sVT[(nb*16 + lr) * 64 + cs]);
                accO[nb] = __builtin_amdgcn_mfma_f32_16x16x32_bf16(ap, bv, accO[nb], 0, 0, 0);
            }
        }
    }

    #pragma unroll
    for (int r = 0; r < 4; ++r) {
        float rinv = __builtin_amdgcn_rcpf(l_row[r]);
        #pragma unroll
        for (int nb = 0; nb < 4; ++nb) {
            int q = q0 + w*16 + lg*4 + r;
            int d = nb*16 + lr;
            Ob[(b * L_ + q) * DM_ + h * DH_ + d] = f2bu(accO[nb][r] * rinv);
        }
    }
}

extern "C" void kernel_launch(void* const* d_in, const int* in_sizes, int n_in,
                              void* d_out, int out_size, void* d_ws, size_t ws_size,
                              hipStream_t stream)
{
    const float* x     = (const float*)d_in[0];
    const float* w_qkv = (const float*)d_in[1];
    const float* w_out = (const float*)d_in[2];
    const float* b_out = (const float*)d_in[3];
    const int*   perms = (const int*)d_in[4];
    float* out = (float*)d_out;

    char* ws = (char*)d_ws;
    size_t off = 0;
    auto alloc_us = [&](size_t elems) -> unsigned short* {
        unsigned short* p = (unsigned short*)(ws + off);
        off += (elems * 2 + 255) & ~(size_t)255;
        return p;
    };
    unsigned short* xb    = alloc_us((size_t)MTOK_ * DM_);
    unsigned short* wqkvb = alloc_us((size_t)NQKV_ * DM_);
    unsigned short* woutb = alloc_us((size_t)DM_ * DM_);
    unsigned short* Qb    = alloc_us((size_t)B_ * H_ * L_ * DH_);
    unsigned short* Kb2   = alloc_us((size_t)B_ * H_ * L_ * DH_);
    unsigned short* VTb   = alloc_us((size_t)B_ * H_ * L_ * DH_);
    unsigned short* SQb   = alloc_us((size_t)B_ * H_ * L_ * DH_);
    unsigned short* Ob    = xb;   // xb dead after QKV GEMM

    cvt_all_k<<<(N_CVT/4 + 255)/256, 256, 0, stream>>>(x, w_qkv, w_out, xb, wqkvb, woutb);

    gemm_bt_k<<<dim3(NQKV_/128, MTOK_/128), 256, 0, stream>>>(
        xb, wqkvb, MTOK_, NQKV_, DM_, 0, Qb, Kb2, VTb, nullptr, nullptr);

    shuffle_q_k<<<(B_*H_*L_*DH_)/256, 256, 0, stream>>>(Qb, perms, SQb);

    attn_k<<<dim3(L_/64, B_*H_), 256, 0, stream>>>(SQb, Kb2, VTb, Ob);

    gemm_bt_k<<<dim3(DM_/128, MTOK_/128), 256, 0, stream>>>(
        Ob, woutb, MTOK_, DM_, DM_, 1, nullptr, nullptr, nullptr, out, b_out);
}

// Round 10
// 268.598 us; speedup vs baseline: 1.1619x; 1.0918x over previous
//
#include <hip/hip_runtime.h>
#include <hip/hip_bf16.h>

#define B_    8
#define L_    1024
#define DM_   768
#define H_    12
#define DH_   64
#define NQKV_ 2304
#define MTOK_ 8192
#define SCALE2 0.1803368801f   // (1/8) * log2(e): softmax computed in exp2 domain

typedef short bf16x8 __attribute__((ext_vector_type(8)));
typedef float f32x4 __attribute__((ext_vector_type(4)));

#define N_X   (MTOK_*DM_)
#define N_WQ  (NQKV_*DM_)
#define N_WO  (DM_*DM_)
#define N_CVT (N_X + N_WQ + N_WO)

// async global->LDS, 16B per lane; LDS dest = uniform base + lane*16 (linear),
// swizzling is done by permuting the per-lane GLOBAL source column (m173 pattern).
#define GLDS16(gp, sp) __builtin_amdgcn_global_load_lds( \
    (const __attribute__((address_space(1))) void*)(gp), \
    (__attribute__((address_space(3))) void*)(sp), 16, 0, 0)

// f32 -> bf16 RNE as raw ushort
static __device__ __forceinline__ unsigned short f2bu(float f) {
    unsigned int x = __float_as_uint(f);
    x = (x + 0x7fffu + ((x >> 16) & 1u)) >> 16;
    return (unsigned short)x;
}

__global__ void cvt_all_k(const float* __restrict__ x, const float* __restrict__ wq,
                          const float* __restrict__ wo,
                          unsigned short* __restrict__ xb, unsigned short* __restrict__ wqb,
                          unsigned short* __restrict__ wob) {
    int i = (blockIdx.x * blockDim.x + threadIdx.x) * 4;
    if (i >= N_CVT) return;
    const float* src; unsigned short* dst; int j = i;
    if (j < N_X)                { src = x;  dst = xb;  }
    else if ((j -= N_X) < N_WQ) { src = wq; dst = wqb; }
    else                        { j -= N_WQ; src = wo; dst = wob; }
    float4 v = *reinterpret_cast<const float4*>(src + j);
    ushort4 o;
    o.x = f2bu(v.x); o.y = f2bu(v.y); o.z = f2bu(v.z); o.w = f2bu(v.w);
    *reinterpret_cast<ushort4*>(dst + j) = o;
}

__global__ void shuffle_q_k(const unsigned short* __restrict__ Qb, const int* __restrict__ perms,
                            unsigned short* __restrict__ SQb) {
    int idx = blockIdx.x * blockDim.x + threadIdx.x;
    int i  = idx & 65535;
    int bh = idx >> 16;
    int h  = bh % H_;
    int p  = perms[h * (L_ * DH_) + i];
    SQb[(bh << 16) + i] = Qb[(bh << 16) + p];
}

static __device__ __forceinline__ int xcd_swz(int bid, int nwg) {
    int cpx = nwg >> 3;
    return (bid & 7) * cpx + (bid >> 3);
}

// C = A[M,K] * Bw[N,K]^T, 128x128 tile, BK=64, global_load_lds staging (m97 structure)
// LDS [128][64] linear; logical col-chunk cc stored at slot cc ^ (row&7)  (conflict-free reads)
// mode 0: scatter Q/K head-major + V TRANSPOSED [b,h][d][key]; mode 1: f32 + bias
__global__ __launch_bounds__(256) void gemm_bt_k(
    const unsigned short* __restrict__ A,
    const unsigned short* __restrict__ Bw,
    int M, int N, int K, int mode,
    unsigned short* __restrict__ Qb, unsigned short* __restrict__ Kb, unsigned short* __restrict__ VTb,
    float* __restrict__ Cout, const float* __restrict__ bias)
{
    __shared__ __align__(16) unsigned short sA[128 * 64];
    __shared__ __align__(16) unsigned short sB[128 * 64];

    int t = threadIdx.x;
    int lane = t & 63, w = t >> 6;
    int wr = w >> 1, wc = w & 1;
    int lr = lane & 15, lg = lane >> 4;

    int nbx = N >> 7;
    int bid = xcd_swz(blockIdx.y * nbx + blockIdx.x, (M >> 7) * nbx);
    int m0 = (bid / nbx) * 128, n0 = (bid % nbx) * 128;

    int srow  = lane >> 3;
    int scol8 = ((lane & 7) ^ srow) * 8;

    f32x4 acc[4][4];
    #pragma unroll
    for (int i = 0; i < 4; ++i)
        #pragma unroll
        for (int j = 0; j < 4; ++j) acc[i][j] = (f32x4){0.f, 0.f, 0.f, 0.f};

    for (int kt = 0; kt < K; kt += 64) {
        __syncthreads();   // prev tile's fragment reads done
        #pragma unroll
        for (int i = 0; i < 4; ++i) {
            int ch = w * 4 + i;
            int row = ch * 8 + srow;
            GLDS16(A  + (size_t)(m0 + row) * K + kt + scol8, sA + ch * 512);
            GLDS16(Bw + (size_t)(n0 + row) * K + kt + scol8, sB + ch * 512);
        }
        __syncthreads();   // drains vmcnt -> LDS ready
        #pragma unroll
        for (int kk = 0; kk < 2; ++kk) {
            int cs = ((kk * 4 + lg) ^ (lr & 7)) << 3;   // swizzled col offset (elems)
            bf16x8 af[4], bfr[4];
            #pragma unroll
            for (int mi = 0; mi < 4; ++mi)
                af[mi] = *reinterpret_cast<const bf16x8*>(&sA[(wr*64 + mi*16 + lr) * 64 + cs]);
            #pragma unroll
            for (int ni = 0; ni < 4; ++ni)
                bfr[ni] = *reinterpret_cast<const bf16x8*>(&sB[(wc*64 + ni*16 + lr) * 64 + cs]);
            #pragma unroll
            for (int mi = 0; mi < 4; ++mi)
                #pragma unroll
                for (int ni = 0; ni < 4; ++ni)
                    acc[mi][ni] = __builtin_amdgcn_mfma_f32_16x16x32_bf16(af[mi], bfr[ni], acc[mi][ni], 0, 0, 0);
        }
    }

    // C/D layout: col = lane&15, row = (lane>>4)*4 + reg (m89/m91)
    if (mode == 0) {
        #pragma unroll
        for (int mi = 0; mi < 4; ++mi)
            #pragma unroll
            for (int ni = 0; ni < 4; ++ni)
                #pragma unroll
                for (int r = 0; r < 4; ++r) {
                    int gm = m0 + wr*64 + mi*16 + lg*4 + r;   // token
                    int gc = n0 + wc*64 + ni*16 + lr;         // qkv column
                    int bidx = gm >> 10, tok = gm & 1023;
                    int which = gc / DM_;
                    int rem = gc - which * DM_;
                    int hh = rem >> 6, d = rem & 63;
                    unsigned short v = f2bu(acc[mi][ni][r]);
                    if (which == 0)      Qb [(((bidx * H_ + hh) * L_) + tok) * DH_ + d] = v;
                    else if (which == 1) Kb [(((bidx * H_ + hh) * L_) + tok) * DH_ + d] = v;
                    else                 VTb[(((bidx * H_ + hh) * DH_) + d) * L_ + tok] = v;  // V^T
                }
    } else {
        #pragma unroll
        for (int mi = 0; mi < 4; ++mi)
            #pragma unroll
            for (int ni = 0; ni < 4; ++ni)
                #pragma unroll
                for (int r = 0; r < 4; ++r) {
                    int gm = m0 + wr*64 + mi*16 + lg*4 + r;
                    int gc = n0 + wc*64 + ni*16 + lr;
                    Cout[(size_t)gm * N + gc] = acc[mi][ni][r] + bias[gc];
                }
    }
}

// Flash attention, swapped-QK^T variant: S^T = mfma(K, Q) so each lane owns ONE q
// (col = lr) and 16 register-contiguous keys (rows). Softmax is in-register +
// 2 wave shuffles; P stored to wave-private sP with 4 packed b64 stores.
// NOTE: softmax stats are per-lane for q = lr; accO rows are q = lg*4+r, so the
// rescale alpha and final 1/l must be shuffled from lane (lg*4+r).
__global__ __launch_bounds__(256) void attn_k(
    const unsigned short* __restrict__ SQb, const unsigned short* __restrict__ Kb,
    const unsigned short* __restrict__ VTb, unsigned short* __restrict__ Ob)
{
    __shared__ __align__(16) unsigned short sQ [64 * 64];
    __shared__ __align__(16) unsigned short sK [64 * 64];
    __shared__ __align__(16) unsigned short sVT[64 * 64];   // [d][key], swizzled
    __shared__ __align__(16) unsigned short sP [4 * 16 * 64];

    int t = threadIdx.x;
    int lane = t & 63, w = t >> 6;
    int lr = lane & 15, lg = lane >> 4;

    int bid = xcd_swz(blockIdx.y * gridDim.x + blockIdx.x, gridDim.x * gridDim.y);
    int bh = bid >> 4;                  // gridDim.x == 16
    int q0 = (bid & 15) * 64;
    int b = bh / H_, h = bh - b * H_;

    const unsigned short* Qp  = SQb + (bh << 16);
    const unsigned short* Kp  = Kb  + (bh << 16);
    const unsigned short* VTp = VTb + (bh << 16);

    int srow  = lane >> 3;
    int scol8 = ((lane & 7) ^ srow) * 8;

    // stage Q once (8 chunks, 2 per wave)
    #pragma unroll
    for (int i = 0; i < 2; ++i) {
        int ch = w * 2 + i;
        int row = ch * 8 + srow;
        GLDS16(Qp + (size_t)(q0 + row) * 64 + scol8, sQ + ch * 512);
    }

    f32x4 accO[4];
    float m_r = -1e30f, l_r = 0.f;
    #pragma unroll
    for (int i = 0; i < 4; ++i) accO[i] = (f32x4){0.f,0.f,0.f,0.f};

    // sP write base: row = lr (q), chunk c = nb*2 + (lg>>1), slot = c ^ (lr&7), sub = (lg&1)*4
    int spw = w * 1024;
    int sp_wr_base = spw + lr * 64 + ((lg & 1) << 2);

    for (int kv0 = 0; kv0 < L_; kv0 += 64) {
        __syncthreads();   // prev tile's sK/sVT reads done
        #pragma unroll
        for (int i = 0; i < 2; ++i) {
            int ch = w * 2 + i;
            int row = ch * 8 + srow;                       // key-row for K, d-row for V^T
            GLDS16(Kp  + (size_t)(kv0 + row) * 64 + scol8, sK  + ch * 512);
            GLDS16(VTp + (size_t)row * L_ + kv0 + scol8,   sVT + ch * 512);
        }
        __syncthreads();   // drain: tiles ready

        // S^T = K x Q^T : A-frag = rows of K (keys), B-frag = rows of Q (q's)
        // D: col = lr = q (w*16+lr), row = key = nb*16 + lg*4 + r
        f32x4 accS[4];
        #pragma unroll
        for (int i = 0; i < 4; ++i) accS[i] = (f32x4){0.f,0.f,0.f,0.f};
        #pragma unroll
        for (int kk = 0; kk < 2; ++kk) {
            int cs = ((kk * 4 + lg) ^ (lr & 7)) << 3;
            bf16x8 aq = *reinterpret_cast<const bf16x8*>(&sQ[(w*16 + lr) * 64 + cs]);
            #pragma unroll
            for (int nb = 0; nb < 4; ++nb) {
                bf16x8 bk = *reinterpret_cast<const bf16x8*>(&sK[(nb*16 + lr) * 64 + cs]);
                accS[nb] = __builtin_amdgcn_mfma_f32_16x16x32_bf16(bk, aq, accS[nb], 0, 0, 0);
            }
        }
        #pragma unroll
        for (int nb = 0; nb < 4; ++nb) accS[nb] *= SCALE2;   // into log2 domain

        // in-register softmax over this lane's 16 keys + 2 cross-lane steps (lg dim)
        float tm = fmaxf(fmaxf(fmaxf(accS[0][0], accS[0][1]), fmaxf(accS[0][2], accS[0][3])),
                         fmaxf(fmaxf(accS[1][0], accS[1][1]), fmaxf(accS[1][2], accS[1][3])));
        tm = fmaxf(tm, fmaxf(fmaxf(fmaxf(accS[2][0], accS[2][1]), fmaxf(accS[2][2], accS[2][3])),
                             fmaxf(fmaxf(accS[3][0], accS[3][1]), fmaxf(accS[3][2], accS[3][3]))));
        tm = fmaxf(tm, __shfl_xor(tm, 16));
        tm = fmaxf(tm, __shfl_xor(tm, 32));
        float mnew  = fmaxf(m_r, tm);
        float alpha = exp2f(m_r - mnew);      // for q = w*16 + lr

        float p[4][4];
        float rs = 0.f;
        #pragma unroll
        for (int nb = 0; nb < 4; ++nb)
            #pragma unroll
            for (int r = 0; r < 4; ++r) {
                float pv = exp2f(accS[nb][r] - mnew);
                p[nb][r] = pv;
                rs += pv;
            }
        rs += __shfl_xor(rs, 16);
        rs += __shfl_xor(rs, 32);
        l_r = l_r * alpha + rs;
        m_r = mnew;

        // pack 4 consecutive keys -> one b64 store per nb (4 dwords/bank = conflict-free)
        #pragma unroll
        for (int nb = 0; nb < 4; ++nb) {
            unsigned int u0 = (unsigned int)f2bu(p[nb][0]) | ((unsigned int)f2bu(p[nb][1]) << 16);
            unsigned int u1 = (unsigned int)f2bu(p[nb][2]) | ((unsigned int)f2bu(p[nb][3]) << 16);
            int slot = (nb*2 + (lg >> 1)) ^ (lr & 7);
            *reinterpret_cast<uint2*>(&sP[sp_wr_base + slot * 8]) = make_uint2(u0, u1);
        }

        // rescale accO: row r holds q = w*16 + lg*4 + r -> needs alpha of lane (lg*4+r)
        #pragma unroll
        for (int r = 0; r < 4; ++r) {
            float a_q = __shfl(alpha, lg * 4 + r);
            #pragma unroll
            for (int nb = 0; nb < 4; ++nb) accO[nb][r] *= a_q;
        }

        // O += P x V : A-frag = rows of sP (q = lr), B-frag = rows of sVT (d)
        // (sP is wave-private: same-wave write->read, lgkmcnt-ordered, no barrier)
        #pragma unroll
        for (int kk = 0; kk < 2; ++kk) {
            int cs = ((kk * 4 + lg) ^ (lr & 7)) << 3;
            bf16x8 ap = *reinterpret_cast<const bf16x8*>(&sP[spw + lr*64 + cs]);
            #pragma unroll
            for (int nb = 0; nb < 4; ++nb) {
                bf16x8 bv = *reinterpret_cast<const bf16x8*>(&sVT[(nb*16 + lr) * 64 + cs]);
                accO[nb] = __builtin_amdgcn_mfma_f32_16x16x32_bf16(ap, bv, accO[nb], 0, 0, 0);
            }
        }
    }

    // accO: row = q = w*16 + lg*4 + r, col = d = nb*16 + lr; l for that q is in lane (lg*4+r)
    #pragma unroll
    for (int r = 0; r < 4; ++r) {
        int qrow = lg * 4 + r;                       // q within wave tile, 0..15
        float lq = __shfl(l_r, qrow);
        float ri = __builtin_amdgcn_rcpf(lq);
        #pragma unroll
        for (int nb = 0; nb < 4; ++nb) {
            int q = q0 + w*16 + qrow;
            int d = nb*16 + lr;
            Ob[(b * L_ + q) * DM_ + h * DH_ + d] = f2bu(accO[nb][r] * ri);
        }
    }
}

extern "C" void kernel_launch(void* const* d_in, const int* in_sizes, int n_in,
                              void* d_out, int out_size, void* d_ws, size_t ws_size,
                              hipStream_t stream)
{
    const float* x     = (const float*)d_in[0];
    const float* w_qkv = (const float*)d_in[1];
    const float* w_out = (const float*)d_in[2];
    const float* b_out = (const float*)d_in[3];
    const int*   perms = (const int*)d_in[4];
    float* out = (float*)d_out;

    char* ws = (char*)d_ws;
    size_t off = 0;
    auto alloc_us = [&](size_t elems) -> unsigned short* {
        unsigned short* p = (unsigned short*)(ws + off);
        off += (elems * 2 + 255) & ~(size_t)255;
        return p;
    };
    unsigned short* xb    = alloc_us((size_t)MTOK_ * DM_);
    unsigned short* wqkvb = alloc_us((size_t)NQKV_ * DM_);
    unsigned short* woutb = alloc_us((size_t)DM_ * DM_);
    unsigned short* Qb    = alloc_us((size_t)B_ * H_ * L_ * DH_);
    unsigned short* Kb2   = alloc_us((size_t)B_ * H_ * L_ * DH_);
    unsigned short* VTb   = alloc_us((size_t)B_ * H_ * L_ * DH_);
    unsigned short* SQb   = alloc_us((size_t)B_ * H_ * L_ * DH_);
    unsigned short* Ob    = xb;   // xb dead after QKV GEMM

    cvt_all_k<<<(N_CVT/4 + 255)/256, 256, 0, stream>>>(x, w_qkv, w_out, xb, wqkvb, woutb);

    gemm_bt_k<<<dim3(NQKV_/128, MTOK_/128), 256, 0, stream>>>(
        xb, wqkvb, MTOK_, NQKV_, DM_, 0, Qb, Kb2, VTb, nullptr, nullptr);

    shuffle_q_k<<<(B_*H_*L_*DH_)/256, 256, 0, stream>>>(Qb, perms, SQb);

    attn_k<<<dim3(L_/64, B_*H_), 256, 0, stream>>>(SQb, Kb2, VTb, Ob);

    gemm_bt_k<<<dim3(DM_/128, MTOK_/128), 256, 0, stream>>>(
        Ob, woutb, MTOK_, DM_, DM_, 1, nullptr, nullptr, nullptr, out, b_out);
}